// Round 8
// baseline (353.986 us; speedup 1.0000x reference)
//
#include <hip/hip_runtime.h>
#include <hip/hip_bf16.h>
#include <hip/hip_fp16.h>
#include <cstddef>

// ---------------------------------------------------------------------------
// GCN 2-layer forward.
//  h1 = relu(Agg(x @ W1) + b1);  out = log_softmax(Agg(h1 @ W2) + b2)
//  Agg(z)[i] = dinv[i]^2 z[i] + sum_{e: col[e]==i} dinv[row] w dinv[i] z[row]
// Round 10: dispatch-count reduction (constant ~140us gap across rounds ~=
// 13-14us x 10 dispatches). 10 -> 8 dispatches:
//  * dinv folded into edge weights at CSR build (w' = w*dinv[src]; dinv is a
//    200KB L2-hot table there) -> GEMMs unscaled -> fusable.
//  * kernelA = hist + global wsum atomics + prep_w (one dispatch).
//  * kernelB = gemm1 || colscan(256-thr pair-scan) || dinv-map (block ranges).
//  * basescan deleted: scatter recomputes bucket-base scan in LDS; block 0
//    publishes bbase/rowptr[n] for bucket_csr.
//  * agg1/agg2 hot loops IDENTICAL to R7 best (4B records, 2-deep pipeline,
//    clamped tail); only self-term now multiplied by dinv in prologue.
// ---------------------------------------------------------------------------

#define DIN 256
#define DH  128
#define DOUT 64
#define NPB 100        // nodes per bucket (50000/100 = 500 buckets)
#define NBMAX 512      // max buckets (shared-array size)

typedef __bf16 bf16x8 __attribute__((ext_vector_type(8)));
typedef float f32x4 __attribute__((ext_vector_type(4)));

__device__ __forceinline__ float bflo(unsigned u) { return __uint_as_float(u << 16); }
__device__ __forceinline__ float bfhi(unsigned u) { return __uint_as_float(u & 0xffff0000u); }
__device__ __forceinline__ unsigned short f2bf(float f) {
    unsigned u = __float_as_uint(f);
    unsigned r = (u + 0x7fffu + ((u >> 16) & 1u)) >> 16;   // round-nearest-even
    return (unsigned short)r;
}
__device__ __forceinline__ float wdec(unsigned rec) {      // fp16 weight in hi16
    return __half2float(__ushort_as_half((unsigned short)(rec >> 16)));
}

// ---------------- Kernel A: hist + wsum atomics + prep_w -------------------
// blocks [0,P): bucket histogram of col + atomicAdd wsum[col] += w
// blocks [P,P+160): weight transpose/convert
__launch_bounds__(256)
__global__ void kernelA(const int* __restrict__ col, const float* __restrict__ ew,
                        int* __restrict__ bh, float* __restrict__ wsum,
                        int E, int Ec, int NB, int P,
                        const float* __restrict__ W1, const float* __restrict__ W2,
                        unsigned short* __restrict__ wt1, unsigned short* __restrict__ wt2) {
    int blk = blockIdx.x, t = threadIdx.x;
    if (blk < P) {
        __shared__ int hist[NBMAX];
        for (int b = t; b < NB; b += 256) hist[b] = 0;
        __syncthreads();
        int s = blk * Ec, e = min(s + Ec, E);
        for (int i = s + t; i < e; i += 256) {
            int c = col[i];
            atomicAdd(&hist[c / NPB], 1);
            atomicAdd(&wsum[c], ew[i]);
        }
        __syncthreads();
        for (int b = t; b < NB; b += 256) bh[blk * NB + b] = hist[b];
    } else {
        int i = (blk - P) * 256 + t;
        if (i < DH * DIN) {                       // wt1 [128][256]
            int nn = i >> 8, k = i & 255;
            wt1[i] = f2bf(W1[k * DH + nn]);
        } else {
            int j = i - DH * DIN;
            if (j < DOUT * DH) {                  // wt2 [64][128]
                int nn = j >> 7, k = j & 127;
                wt2[j] = f2bf(W2[k * DOUT + nn]);
            }
        }
    }
}

// ---------------- unscaled MFMA GEMM body (shared by B and gemm2) ----------
// C[r][:] = bf16(A[r][:K] @ B), Wt = B^T bf16 [M][K]. 64 rows/block, 4 waves.
template <int K, int M>
__device__ __forceinline__ void gemm_body(const float* __restrict__ A,
                                          const unsigned short* __restrict__ Wt,
                                          unsigned short* __restrict__ C,
                                          int N, int blk, int tid, char* smemRaw) {
    constexpr int BK = 64, LD = BK + 8;
    constexpr int WN = M / 4;
    constexpr int NT = WN / 16;
    constexpr int CLD = M + 8;
    unsigned short* smem = (unsigned short*)smemRaw;
    unsigned short* As = smem;                // [64][LD]
    unsigned short* Bs = smem + 64 * LD;      // [M][LD]

    const int row0 = blk * 64;
    const int lane = tid & 63;
    const int quad = lane >> 4, r16 = lane & 15;
    const int n0 = (tid >> 6) * WN;

    f32x4 acc[4][NT];
#pragma unroll
    for (int mt = 0; mt < 4; ++mt)
#pragma unroll
        for (int nt = 0; nt < NT; ++nt)
            acc[mt][nt] = (f32x4){0.f, 0.f, 0.f, 0.f};

    for (int k0 = 0; k0 < K; k0 += BK) {
#pragma unroll
        for (int j = 0; j < 4; ++j) {
            int idx = tid + j * 256;
            int m = idx >> 4;
            int q = idx & 15;
            int gr = row0 + m;
            float4 v = make_float4(0.f, 0.f, 0.f, 0.f);
            if (gr < N) v = *(const float4*)&A[(size_t)gr * K + k0 + q * 4];
            ushort4 s4;
            s4.x = f2bf(v.x); s4.y = f2bf(v.y); s4.z = f2bf(v.z); s4.w = f2bf(v.w);
            *(ushort4*)&As[m * LD + q * 4] = s4;
        }
#pragma unroll
        for (int j = 0; j < M * 8 / 256; ++j) {
            int idx = tid + j * 256;
            int nn = idx >> 3;
            int q = idx & 7;
            uint4 v = *(const uint4*)&Wt[(size_t)nn * K + k0 + q * 8];
            *(uint4*)&Bs[nn * LD + q * 8] = v;
        }
        __syncthreads();
#pragma unroll
        for (int ks = 0; ks < BK / 32; ++ks) {
            bf16x8 af[4], bfr[NT];
#pragma unroll
            for (int nt = 0; nt < NT; ++nt)
                bfr[nt] = *(const bf16x8*)&Bs[(n0 + nt * 16 + r16) * LD + ks * 32 + quad * 8];
#pragma unroll
            for (int mt = 0; mt < 4; ++mt)
                af[mt] = *(const bf16x8*)&As[(mt * 16 + r16) * LD + ks * 32 + quad * 8];
#pragma unroll
            for (int mt = 0; mt < 4; ++mt)
#pragma unroll
                for (int nt = 0; nt < NT; ++nt)
                    acc[mt][nt] = __builtin_amdgcn_mfma_f32_16x16x32_bf16(
                        af[mt], bfr[nt], acc[mt][nt], 0, 0, 0);
        }
        __syncthreads();
    }
    unsigned short* Cs = smem;                // [64][CLD]
#pragma unroll
    for (int mt = 0; mt < 4; ++mt) {
#pragma unroll
        for (int i = 0; i < 4; ++i) {
            int r = mt * 16 + quad * 4 + i;
#pragma unroll
            for (int nt = 0; nt < NT; ++nt)
                Cs[r * CLD + n0 + nt * 16 + r16] = f2bf(acc[mt][nt][i]);
        }
    }
    __syncthreads();
#pragma unroll
    for (int j = 0; j < 64 * M / 8 / 256; ++j) {
        int idx = tid + j * 256;
        int r = idx / (M / 8);
        int q = idx % (M / 8);
        int gr = row0 + r;
        if (gr < N) {
            uint4 v = *(const uint4*)&Cs[r * CLD + q * 8];
            *(uint4*)&C[(size_t)gr * M + q * 8] = v;
        }
    }
}

// ---------------- Kernel B: gemm1 || colscan || dinv-map -------------------
// blocks [0,nbg1): gemm1 (x @ W1 -> bf16 xw1, unscaled)
// blocks [nbg1, nbg1+NB): per-bucket column scan of bh (pair-scan, 256 thr)
// blocks [nbg1+NB, ...): dinv[i] = rsqrt(1 + wsum[i])
__launch_bounds__(256)
__global__ void kernelB(const float* __restrict__ x, const unsigned short* __restrict__ wt1,
                        unsigned short* __restrict__ xw1, int n,
                        int* __restrict__ bh, int* __restrict__ btotal, int P, int NB,
                        int nbg1, const float* __restrict__ wsum, float* __restrict__ dinv) {
    __shared__ char smemRaw[(64 * 72 + DH * 72) * 2];
    int blk = blockIdx.x, t = threadIdx.x;
    if (blk < nbg1) {
        gemm_body<DIN, DH>(x, wt1, xw1, n, blk, t, smemRaw);
    } else if (blk < nbg1 + NB) {
        int b = blk - nbg1;
        int* ps = (int*)smemRaw;              // [256]
        int i0 = 2 * t, i1 = 2 * t + 1;
        int x0 = (i0 < P) ? bh[i0 * NB + b] : 0;
        int x1 = (i1 < P) ? bh[i1 * NB + b] : 0;
        int s = x0 + x1;
        ps[t] = s;
        __syncthreads();
        for (int off = 1; off < 256; off <<= 1) {
            int v = (t >= off) ? ps[t - off] : 0;
            __syncthreads();
            ps[t] += v;
            __syncthreads();
        }
        int excl = ps[t] - s;                 // exclusive over pairs
        if (i0 < P) bh[i0 * NB + b] = excl;
        if (i1 < P) bh[i1 * NB + b] = excl + x0;
        if (t == 255) btotal[b] = ps[255];
    } else {
        int i = (blk - nbg1 - NB) * 256 + t;
        if (i < n) dinv[i] = rsqrtf(1.0f + wsum[i]);
    }
}

// ---------------- scatter with inline bucket-base scan ---------------------
// part[pos] = (row | col_local<<16, w_bits). Block 0 publishes bbase + rowptr[n].
__launch_bounds__(256)
__global__ void scatter_kernel(const int* __restrict__ row, const int* __restrict__ col,
                               const float* __restrict__ w, const int* __restrict__ bh,
                               const int* __restrict__ btotal, int* __restrict__ bbase,
                               int* __restrict__ rowptr, int2* __restrict__ part,
                               int E, int Ec, int NB, int n) {
    __shared__ int ps[256];
    __shared__ int bb[NBMAX];
    __shared__ int cur[NBMAX];
    int p = blockIdx.x, t = threadIdx.x;
    // exclusive scan of btotal[0..NB) via pair-scan
    int i0 = 2 * t, i1 = 2 * t + 1;
    int x0 = (i0 < NB) ? btotal[i0] : 0;
    int x1 = (i1 < NB) ? btotal[i1] : 0;
    int s = x0 + x1;
    ps[t] = s;
    __syncthreads();
    for (int off = 1; off < 256; off <<= 1) {
        int v = (t >= off) ? ps[t - off] : 0;
        __syncthreads();
        ps[t] += v;
        __syncthreads();
    }
    int excl = ps[t] - s;
    if (i0 < NB) bb[i0] = excl;
    if (i1 < NB) bb[i1] = excl + x0;
    __syncthreads();
    for (int b = t; b < NB; b += 256) cur[b] = bb[b] + bh[p * NB + b];
    if (p == 0) {                               // publish for bucket_csr
        if (i0 < NB) bbase[i0] = bb[i0];
        if (i1 < NB) bbase[i1] = bb[i1];
        if (t == 255) { bbase[NB] = ps[255]; rowptr[n] = E; }
    }
    __syncthreads();
    int s0 = p * Ec, e = min(s0 + Ec, E);
    for (int i = s0 + t; i < e; i += 256) {
        int c = col[i];
        int r = row[i];
        int b = c / NPB;
        int pos = atomicAdd(&cur[b], 1);          // LDS atomic
        part[pos] = make_int2(r | ((c - b * NPB) << 16), __float_as_int(w[i]));
    }
}

// ---------------- bucket_csr: per-node rowptr + CSR w/ folded dinv ---------
// Edge record 4B: src(u16) | half(w * dinv[src]) << 16.
__launch_bounds__(256)
__global__ void bucket_csr_kernel(const int2* __restrict__ part, const int* __restrict__ bbase,
                                  const float* __restrict__ dinv, int* __restrict__ rowptr,
                                  unsigned* __restrict__ final_e, int n) {
    __shared__ int   hist[NPB];
    __shared__ int   nbase[NPB];
    __shared__ int   cur[NPB];
    int b = blockIdx.x, t = threadIdx.x;
    if (t < NPB) hist[t] = 0;
    __syncthreads();
    int s = bbase[b], e = bbase[b + 1];
    for (int i = s + t; i < e; i += 256) {
        int2 rec = part[i];
        atomicAdd(&hist[rec.x >> 16], 1);
    }
    __syncthreads();
    if (t == 0) {
        int run = 0;
        for (int k = 0; k < NPB; ++k) { nbase[k] = run; run += hist[k]; }
    }
    __syncthreads();
    if (t < NPB) {
        int node = b * NPB + t;
        if (node < n) rowptr[node] = s + nbase[t];
        cur[t] = nbase[t];
    }
    __syncthreads();
    for (int i = s + t; i < e; i += 256) {
        int2 rec = part[i];
        int cl = rec.x >> 16;
        int q = s + atomicAdd(&cur[cl], 1);       // LDS atomic
        int src = rec.x & 0xffff;
        float wp = __int_as_float(rec.y) * dinv[src];   // dinv: 200KB, L2-hot
        unsigned short ws = __half_as_ushort(__float2half_rn(wp));
        final_e[q] = (unsigned)src | ((unsigned)ws << 16);
    }
}

// ---------------- standalone gemm2 (unscaled) ------------------------------
template <int K, int M>
__launch_bounds__(256)
__global__ void gemm_kernel(const float* __restrict__ A, const unsigned short* __restrict__ Wt,
                            unsigned short* __restrict__ C, int N) {
    __shared__ char smemRaw[(64 * 72 + M * 72) * 2];
    gemm_body<K, M>(A, Wt, C, N, blockIdx.x, threadIdx.x, smemRaw);
}

#define ACC8(v, wgt)                                            \
    a0 += (wgt) * bflo((v).x); a1 += (wgt) * bfhi((v).x);       \
    a2 += (wgt) * bflo((v).y); a3 += (wgt) * bfhi((v).y);       \
    a4 += (wgt) * bflo((v).z); a5 += (wgt) * bfhi((v).z);       \
    a6 += (wgt) * bflo((v).w); a7 += (wgt) * bfhi((v).w);

// Layer-1 aggregation (R7 structure): 1 wave/node, 4 slots x 16 lanes,
// uint4 full-row gathers, 2-deep pipeline. Self term scaled by dinv here
// (table is unscaled t = x@W1; edges carry w' = w*dinv[src]).
__launch_bounds__(256, 6)
__global__ void agg1_kernel(const unsigned short* __restrict__ xw,   // bf16 [n][128]
                            const int* __restrict__ rowptr,
                            const unsigned* __restrict__ edge,       // src|half(w')<<16
                            const float* __restrict__ dinv,
                            const float* __restrict__ bias,          // fp32 [128]
                            float* __restrict__ out, int n) {        // fp32 [n][128]
    int node = blockIdx.x * 4 + (threadIdx.x >> 6);
    if (node >= n) return;
    int lane = threadIdx.x & 63;
    int qw = lane >> 4, sub = lane & 15;
    const char* xb = (const char*)xw;
    const unsigned ssub = (unsigned)sub << 4;       // byte offset in 256B row
    float di = dinv[node];

    float a0 = 0.f, a1 = 0.f, a2 = 0.f, a3 = 0.f;
    float a4 = 0.f, a5 = 0.f, a6 = 0.f, a7 = 0.f;
    if (qw == 0) {                                   // self term, weight dinv
        uint4 u = *(const uint4*)(xb + (((unsigned)node) << 8) + ssub);
        a0 = di * bflo(u.x); a1 = di * bfhi(u.x); a2 = di * bflo(u.y); a3 = di * bfhi(u.y);
        a4 = di * bflo(u.z); a5 = di * bfhi(u.z); a6 = di * bflo(u.w); a7 = di * bfhi(u.w);
    }

    int p = rowptr[node], p1 = rowptr[node + 1];
    int sb = 4 * qw;
    unsigned r0, r1, r2, r3;
    uint4 v0, v1, v2, v3;
    bool have = (p + 16 <= p1);
    if (have) {
        const unsigned* rp = edge + p + sb;
        r0 = __builtin_nontemporal_load(rp);
        r1 = __builtin_nontemporal_load(rp + 1);
        r2 = __builtin_nontemporal_load(rp + 2);
        r3 = __builtin_nontemporal_load(rp + 3);
        v0 = *(const uint4*)(xb + ((r0 & 0xffffu) << 8) + ssub);
        v1 = *(const uint4*)(xb + ((r1 & 0xffffu) << 8) + ssub);
        v2 = *(const uint4*)(xb + ((r2 & 0xffffu) << 8) + ssub);
        v3 = *(const uint4*)(xb + ((r3 & 0xffffu) << 8) + ssub);
    }
#pragma unroll 1
    while (have) {
        p += 16;
        bool havn = (p + 16 <= p1);
        unsigned m0 = 0, m1 = 0, m2 = 0, m3 = 0;
        uint4 u0 = {0,0,0,0}, u1 = {0,0,0,0}, u2 = {0,0,0,0}, u3 = {0,0,0,0};
        if (havn) {                                  // next records + gathers
            const unsigned* rp = edge + p + sb;
            m0 = __builtin_nontemporal_load(rp);
            m1 = __builtin_nontemporal_load(rp + 1);
            m2 = __builtin_nontemporal_load(rp + 2);
            m3 = __builtin_nontemporal_load(rp + 3);
            u0 = *(const uint4*)(xb + ((m0 & 0xffffu) << 8) + ssub);
            u1 = *(const uint4*)(xb + ((m1 & 0xffffu) << 8) + ssub);
            u2 = *(const uint4*)(xb + ((m2 & 0xffffu) << 8) + ssub);
            u3 = *(const uint4*)(xb + ((m3 & 0xffffu) << 8) + ssub);
        }
        float w0 = wdec(r0), w1 = wdec(r1), w2 = wdec(r2), w3 = wdec(r3);
        ACC8(v0, w0); ACC8(v1, w1); ACC8(v2, w2); ACC8(v3, w3);
        r0 = m0; r1 = m1; r2 = m2; r3 = m3;
        v0 = u0; v1 = u1; v2 = u2; v3 = u3;
        have = havn;
    }
    int rem = p1 - p;                                // 0..15, one clamped round
    if (rem > 0) {
        int last = p1 - 1, b = p + sb;
        unsigned e0 = edge[min(b, last)],     e1 = edge[min(b + 1, last)];
        unsigned e2 = edge[min(b + 2, last)], e3 = edge[min(b + 3, last)];
        float w0 = (b     <= last) ? wdec(e0) : 0.f;
        float w1 = (b + 1 <= last) ? wdec(e1) : 0.f;
        float w2 = (b + 2 <= last) ? wdec(e2) : 0.f;
        float w3 = (b + 3 <= last) ? wdec(e3) : 0.f;
        uint4 t0 = *(const uint4*)(xb + ((e0 & 0xffffu) << 8) + ssub);
        uint4 t1 = *(const uint4*)(xb + ((e1 & 0xffffu) << 8) + ssub);
        uint4 t2 = *(const uint4*)(xb + ((e2 & 0xffffu) << 8) + ssub);
        uint4 t3 = *(const uint4*)(xb + ((e3 & 0xffffu) << 8) + ssub);
        ACC8(t0, w0); ACC8(t1, w1); ACC8(t2, w2); ACC8(t3, w3);
    }
    // reduce over the 4 slots (lane bits 4,5)
    a0 += __shfl_xor(a0, 16); a0 += __shfl_xor(a0, 32);
    a1 += __shfl_xor(a1, 16); a1 += __shfl_xor(a1, 32);
    a2 += __shfl_xor(a2, 16); a2 += __shfl_xor(a2, 32);
    a3 += __shfl_xor(a3, 16); a3 += __shfl_xor(a3, 32);
    a4 += __shfl_xor(a4, 16); a4 += __shfl_xor(a4, 32);
    a5 += __shfl_xor(a5, 16); a5 += __shfl_xor(a5, 32);
    a6 += __shfl_xor(a6, 16); a6 += __shfl_xor(a6, 32);
    a7 += __shfl_xor(a7, 16); a7 += __shfl_xor(a7, 32);
    if (qw < 2) {
        float4 b = ((const float4*)bias)[2 * sub + qw];
        f32x4 o;
        if (qw == 0) { o.x = a0; o.y = a1; o.z = a2; o.w = a3; }
        else         { o.x = a4; o.y = a5; o.z = a6; o.w = a7; }
        o.x = fmaxf(di * o.x + b.x, 0.f);
        o.y = fmaxf(di * o.y + b.y, 0.f);
        o.z = fmaxf(di * o.z + b.z, 0.f);
        o.w = fmaxf(di * o.w + b.w, 0.f);
        __builtin_nontemporal_store(o, (f32x4*)out + (size_t)node * 32 + 2 * sub + qw);
    }
}

// Layer-2 aggregation + log_softmax (R7 structure): 8 slots x 8 lanes.
__launch_bounds__(256, 6)
__global__ void agg2_kernel(const unsigned short* __restrict__ xw,   // bf16 [n][64]
                            const int* __restrict__ rowptr,
                            const unsigned* __restrict__ edge,
                            const float* __restrict__ dinv,
                            const float* __restrict__ bias,          // fp32 [64]
                            float* __restrict__ out, int n) {        // fp32 [n][64]
    int node = blockIdx.x * 4 + (threadIdx.x >> 6);
    if (node >= n) return;
    int lane = threadIdx.x & 63;
    int oct = lane >> 3, sub = lane & 7;
    const char* xb = (const char*)xw;
    const unsigned ssub = (unsigned)sub << 4;       // byte offset in 128B row
    float di = dinv[node];

    float a0 = 0.f, a1 = 0.f, a2 = 0.f, a3 = 0.f;
    float a4 = 0.f, a5 = 0.f, a6 = 0.f, a7 = 0.f;
    if (oct == 0) {                                  // self term, weight dinv
        uint4 u = *(const uint4*)(xb + (((unsigned)node) << 7) + ssub);
        a0 = di * bflo(u.x); a1 = di * bfhi(u.x); a2 = di * bflo(u.y); a3 = di * bfhi(u.y);
        a4 = di * bflo(u.z); a5 = di * bfhi(u.z); a6 = di * bflo(u.w); a7 = di * bfhi(u.w);
    }

    int p = rowptr[node], p1 = rowptr[node + 1];
    int sb = 4 * oct;
    unsigned r0, r1, r2, r3;
    uint4 v0, v1, v2, v3;
    bool have = (p + 32 <= p1);
    if (have) {
        const unsigned* rp = edge + p + sb;
        r0 = __builtin_nontemporal_load(rp);
        r1 = __builtin_nontemporal_load(rp + 1);
        r2 = __builtin_nontemporal_load(rp + 2);
        r3 = __builtin_nontemporal_load(rp + 3);
        v0 = *(const uint4*)(xb + ((r0 & 0xffffu) << 7) + ssub);
        v1 = *(const uint4*)(xb + ((r1 & 0xffffu) << 7) + ssub);
        v2 = *(const uint4*)(xb + ((r2 & 0xffffu) << 7) + ssub);
        v3 = *(const uint4*)(xb + ((r3 & 0xffffu) << 7) + ssub);
    }
#pragma unroll 1
    while (have) {
        p += 32;
        bool havn = (p + 32 <= p1);
        unsigned m0 = 0, m1 = 0, m2 = 0, m3 = 0;
        uint4 u0 = {0,0,0,0}, u1 = {0,0,0,0}, u2 = {0,0,0,0}, u3 = {0,0,0,0};
        if (havn) {
            const unsigned* rp = edge + p + sb;
            m0 = __builtin_nontemporal_load(rp);
            m1 = __builtin_nontemporal_load(rp + 1);
            m2 = __builtin_nontemporal_load(rp + 2);
            m3 = __builtin_nontemporal_load(rp + 3);
            u0 = *(const uint4*)(xb + ((m0 & 0xffffu) << 7) + ssub);
            u1 = *(const uint4*)(xb + ((m1 & 0xffffu) << 7) + ssub);
            u2 = *(const uint4*)(xb + ((m2 & 0xffffu) << 7) + ssub);
            u3 = *(const uint4*)(xb + ((m3 & 0xffffu) << 7) + ssub);
        }
        float w0 = wdec(r0), w1 = wdec(r1), w2 = wdec(r2), w3 = wdec(r3);
        ACC8(v0, w0); ACC8(v1, w1); ACC8(v2, w2); ACC8(v3, w3);
        r0 = m0; r1 = m1; r2 = m2; r3 = m3;
        v0 = u0; v1 = u1; v2 = u2; v3 = u3;
        have = havn;
    }
    int rem = p1 - p;                                // 0..31, one clamped round
    if (rem > 0) {
        int last = p1 - 1, b = p + sb;
        unsigned e0 = edge[min(b, last)],     e1 = edge[min(b + 1, last)];
        unsigned e2 = edge[min(b + 2, last)], e3 = edge[min(b + 3, last)];
        float w0 = (b     <= last) ? wdec(e0) : 0.f;
        float w1 = (b + 1 <= last) ? wdec(e1) : 0.f;
        float w2 = (b + 2 <= last) ? wdec(e2) : 0.f;
        float w3 = (b + 3 <= last) ? wdec(e3) : 0.f;
        uint4 t0 = *(const uint4*)(xb + ((e0 & 0xffffu) << 7) + ssub);
        uint4 t1 = *(const uint4*)(xb + ((e1 & 0xffffu) << 7) + ssub);
        uint4 t2 = *(const uint4*)(xb + ((e2 & 0xffffu) << 7) + ssub);
        uint4 t3 = *(const uint4*)(xb + ((e3 & 0xffffu) << 7) + ssub);
        ACC8(t0, w0); ACC8(t1, w1); ACC8(t2, w2); ACC8(t3, w3);
    }
    // reduce over the 8 slots (lane bits 3,4,5)
    a0 += __shfl_xor(a0, 8); a0 += __shfl_xor(a0, 16); a0 += __shfl_xor(a0, 32);
    a1 += __shfl_xor(a1, 8); a1 += __shfl_xor(a1, 16); a1 += __shfl_xor(a1, 32);
    a2 += __shfl_xor(a2, 8); a2 += __shfl_xor(a2, 16); a2 += __shfl_xor(a2, 32);
    a3 += __shfl_xor(a3, 8); a3 += __shfl_xor(a3, 16); a3 += __shfl_xor(a3, 32);
    a4 += __shfl_xor(a4, 8); a4 += __shfl_xor(a4, 16); a4 += __shfl_xor(a4, 32);
    a5 += __shfl_xor(a5, 8); a5 += __shfl_xor(a5, 16); a5 += __shfl_xor(a5, 32);
    a6 += __shfl_xor(a6, 8); a6 += __shfl_xor(a6, 16); a6 += __shfl_xor(a6, 32);
    a7 += __shfl_xor(a7, 8); a7 += __shfl_xor(a7, 16); a7 += __shfl_xor(a7, 32);
    // bias + dinv, then log_softmax over the 64 features
    const float4* bp = (const float4*)bias;
    float4 bl = bp[2 * sub], bh = bp[2 * sub + 1];
    a0 = di * a0 + bl.x; a1 = di * a1 + bl.y; a2 = di * a2 + bl.z; a3 = di * a3 + bl.w;
    a4 = di * a4 + bh.x; a5 = di * a5 + bh.y; a6 = di * a6 + bh.z; a7 = di * a7 + bh.w;
    float m = fmaxf(fmaxf(fmaxf(a0, a1), fmaxf(a2, a3)),
                    fmaxf(fmaxf(a4, a5), fmaxf(a6, a7)));
    m = fmaxf(m, __shfl_xor(m, 4));
    m = fmaxf(m, __shfl_xor(m, 2));
    m = fmaxf(m, __shfl_xor(m, 1));
    float s = __expf(a0 - m) + __expf(a1 - m) + __expf(a2 - m) + __expf(a3 - m)
            + __expf(a4 - m) + __expf(a5 - m) + __expf(a6 - m) + __expf(a7 - m);
    s += __shfl_xor(s, 4);
    s += __shfl_xor(s, 2);
    s += __shfl_xor(s, 1);
    float lse = m + __logf(s);
    if (oct < 2) {
        f32x4 o;
        if (oct == 0) { o.x = a0 - lse; o.y = a1 - lse; o.z = a2 - lse; o.w = a3 - lse; }
        else          { o.x = a4 - lse; o.y = a5 - lse; o.z = a6 - lse; o.w = a7 - lse; }
        __builtin_nontemporal_store(o, (f32x4*)out + (size_t)node * 16 + 2 * sub + oct);
    }
}

extern "C" void kernel_launch(void* const* d_in, const int* in_sizes, int n_in,
                              void* d_out, int out_size, void* d_ws, size_t ws_size,
                              hipStream_t stream) {
    const float* x  = (const float*)d_in[0];
    const int*   ei = (const int*)d_in[1];
    const float* ew = (const float*)d_in[2];
    const float* W1 = (const float*)d_in[3];
    const float* b1 = (const float*)d_in[4];
    const float* W2 = (const float*)d_in[5];
    const float* b2 = (const float*)d_in[6];
    float* out = (float*)d_out;

    const int n = in_sizes[0] / DIN;      // 50000
    const int E = in_sizes[2];            // 1600000
    const int* row = ei;                  // edge_index[0] (source)
    const int* col = ei + E;              // edge_index[1] (target)

    const int NB = (n + NPB - 1) / NPB;   // 500 buckets
    const int P  = NB;
    const int Ec = (E + P - 1) / P;       // 3200 edges/block

    char* ptr = (char*)d_ws;
    auto alloc = [&](size_t bytes) -> void* {
        void* r = (void*)ptr;
        ptr += (bytes + 255) & ~(size_t)255;
        return r;
    };
    int*   bh     = (int*)  alloc((size_t)P * NB * 4);       // 1 MB
    int*   btotal = (int*)  alloc((size_t)NB * 4);
    int*   bbase  = (int*)  alloc((size_t)(NB + 1) * 4);
    int*   rowptr = (int*)  alloc((size_t)(n + 1) * 4);
    float* dinv   = (float*)alloc((size_t)n * 4);
    float* wsum   = (float*)alloc((size_t)n * 4);
    unsigned* edge = (unsigned*)alloc((size_t)E * 4);        // packed CSR edges
    unsigned short* xw1 = (unsigned short*)alloc((size_t)n * DH * 2);  // bf16 tables
    unsigned short* wt1 = (unsigned short*)alloc((size_t)DH * DIN * 2);
    unsigned short* wt2 = (unsigned short*)alloc((size_t)DOUT * DH * 2);
    // tail: part (12.8MB, build phase) then h1 (25.6MB, compute phase)
    char* tail = (char*)alloc((size_t)n * DH * 4);
    int2*  part = (int2*)tail;
    float* h1   = (float*)tail;
    unsigned short* xw2 = xw1;            // layer-2 table aliases layer-1 table

    const int nbg1 = (n + 63) / 64;       // 782
    const int ndiv = (n + 255) / 256;     // 196
    const int nb_a = (n + 3) / 4;         // 12500
    const int prepb = (DH * DIN + DOUT * DH + 255) / 256;    // 160

    hipMemsetAsync(wsum, 0, (size_t)n * 4, stream);
    kernelA<<<P + prepb, 256, 0, stream>>>(col, ew, bh, wsum, E, Ec, NB, P, W1, W2, wt1, wt2);
    kernelB<<<nbg1 + NB + ndiv, 256, 0, stream>>>(x, wt1, xw1, n, bh, btotal, P, NB, nbg1, wsum, dinv);
    scatter_kernel<<<P, 256, 0, stream>>>(row, col, ew, bh, btotal, bbase, rowptr, part, E, Ec, NB, n);
    bucket_csr_kernel<<<NB, 256, 0, stream>>>(part, bbase, dinv, rowptr, edge, n);
    agg1_kernel<<<nb_a, 256, 0, stream>>>(xw1, rowptr, edge, dinv, b1, h1, n);
    gemm_kernel<DH, DOUT><<<nbg1, 256, 0, stream>>>(h1, wt2, xw2, n);
    agg2_kernel<<<nb_a, 256, 0, stream>>>(xw2, rowptr, edge, dinv, b2, out, n);
}

// Round 9
// 267.530 us; speedup vs baseline: 1.3232x; 1.3232x over previous
//
#include <hip/hip_runtime.h>
#include <hip/hip_bf16.h>
#include <hip/hip_fp16.h>
#include <cstddef>

// ---------------------------------------------------------------------------
// GCN 2-layer forward.
//  h1 = relu(Agg(x @ W1) + b1);  out = log_softmax(Agg(h1 @ W2) + b2)
//  Agg(z)[i] = dinv[i]^2 z[i] + sum_{e: col[e]==i} dinv[row] w dinv[i] z[row]
// Round 11: revert to R7 build (276us best) + 2 SAFE fusions (10->8 dispatch).
//  * R10 post-mortem: global wsum atomics = 92us latency chain (VALU 0.6%).
//    wsum back in bucket_csr's LDS (bucket-partitioned, uncontended).
//  * kernelA = hist + prep_w via block-range split (independent work).
//  * basescan deleted: scatter scans btotal inline in LDS; block 0 publishes
//    bbase + rowptr[n].
//  * colscan / bucket_csr / scaled-GEMM / agg1 / agg2 byte-identical to R7.
// ---------------------------------------------------------------------------

#define DIN 256
#define DH  128
#define DOUT 64
#define NPB 100        // nodes per bucket (50000/100 = 500 buckets)
#define NBMAX 512      // max buckets (shared-array size)

typedef __bf16 bf16x8 __attribute__((ext_vector_type(8)));
typedef float f32x4 __attribute__((ext_vector_type(4)));

__device__ __forceinline__ float bflo(unsigned u) { return __uint_as_float(u << 16); }
__device__ __forceinline__ float bfhi(unsigned u) { return __uint_as_float(u & 0xffff0000u); }
__device__ __forceinline__ unsigned short f2bf(float f) {
    unsigned u = __float_as_uint(f);
    unsigned r = (u + 0x7fffu + ((u >> 16) & 1u)) >> 16;   // round-nearest-even
    return (unsigned short)r;
}
__device__ __forceinline__ float wdec(unsigned rec) {      // fp16 weight in hi16
    return __half2float(__ushort_as_half((unsigned short)(rec >> 16)));
}

// ---------------- Kernel A: hist || prep_w (block-range split) -------------
__launch_bounds__(256)
__global__ void kernelA(const int* __restrict__ col, int* __restrict__ bh,
                        int E, int Ec, int NB, int P,
                        const float* __restrict__ W1, const float* __restrict__ W2,
                        unsigned short* __restrict__ wt1, unsigned short* __restrict__ wt2) {
    int blk = blockIdx.x, t = threadIdx.x;
    if (blk < P) {
        __shared__ int hist[NBMAX];
        for (int b = t; b < NB; b += 256) hist[b] = 0;
        __syncthreads();
        int s = blk * Ec, e = min(s + Ec, E);
        for (int i = s + t; i < e; i += 256) atomicAdd(&hist[col[i] / NPB], 1);
        __syncthreads();
        for (int b = t; b < NB; b += 256) bh[blk * NB + b] = hist[b];
    } else {
        int i = (blk - P) * 256 + t;
        if (i < DH * DIN) {                       // wt1 [128][256]
            int nn = i >> 8, k = i & 255;
            wt1[i] = f2bf(W1[k * DH + nn]);
        } else {
            int j = i - DH * DIN;
            if (j < DOUT * DH) {                  // wt2 [64][128]
                int nn = j >> 7, k = j & 127;
                wt2[j] = f2bf(W2[k * DOUT + nn]);
            }
        }
    }
}

// Pass 2: per-bucket column scan over blocks (exclusive, in place). [R7]
__launch_bounds__(512)
__global__ void colscan_kernel(int* __restrict__ bh, int* __restrict__ btotal,
                               int P, int NB) {
    __shared__ int arr[512];
    int b = blockIdx.x, t = threadIdx.x;
    arr[t] = (t < P) ? bh[t * NB + b] : 0;
    __syncthreads();
    for (int off = 1; off < 512; off <<= 1) {
        int v = (t >= off) ? arr[t - off] : 0;
        __syncthreads();
        arr[t] += v;
        __syncthreads();
    }
    int excl = (t == 0) ? 0 : arr[t - 1];
    if (t < P) bh[t * NB + b] = excl;
    if (t == P - 1) btotal[b] = arr[t];
}

// Pass 3: scatter with inline bucket-base scan. Block 0 publishes bbase +
// rowptr[n]. part[pos] = (row | col_local<<16, w_bits fp32).
__launch_bounds__(256)
__global__ void scatter_kernel(const int* __restrict__ row, const int* __restrict__ col,
                               const float* __restrict__ w, const int* __restrict__ bh,
                               const int* __restrict__ btotal, int* __restrict__ bbase,
                               int* __restrict__ rowptr, int2* __restrict__ part,
                               int E, int Ec, int NB, int n) {
    __shared__ int ps[256];
    __shared__ int bb[NBMAX];
    __shared__ int cur[NBMAX];
    int p = blockIdx.x, t = threadIdx.x;
    // exclusive scan of btotal[0..NB) via pair-scan
    int i0 = 2 * t, i1 = 2 * t + 1;
    int x0 = (i0 < NB) ? btotal[i0] : 0;
    int x1 = (i1 < NB) ? btotal[i1] : 0;
    int s = x0 + x1;
    ps[t] = s;
    __syncthreads();
    for (int off = 1; off < 256; off <<= 1) {
        int v = (t >= off) ? ps[t - off] : 0;
        __syncthreads();
        ps[t] += v;
        __syncthreads();
    }
    int excl = ps[t] - s;
    if (i0 < NB) bb[i0] = excl;
    if (i1 < NB) bb[i1] = excl + x0;
    __syncthreads();
    for (int b = t; b < NB; b += 256) cur[b] = bb[b] + bh[p * NB + b];
    if (p == 0) {                               // publish for bucket_csr
        if (i0 < NB) bbase[i0] = bb[i0];
        if (i1 < NB) bbase[i1] = bb[i1];
        if (t == 255) { bbase[NB] = ps[255]; rowptr[n] = E; }
    }
    __syncthreads();
    int s0 = p * Ec, e = min(s0 + Ec, E);
    for (int i = s0 + t; i < e; i += 256) {
        int c = col[i];
        int r = row[i];
        int b = c / NPB;
        int pos = atomicAdd(&cur[b], 1);          // LDS atomic
        part[pos] = make_int2(r | ((c - b * NPB) << 16), __float_as_int(w[i]));
    }
}

// Pass 4: one block per bucket: per-node deg/dinv/rowptr + per-node CSR. [R7]
// Edge record packed to 4B: src(u16) | half(RAW w)<<16.
__launch_bounds__(256)
__global__ void bucket_csr_kernel(const int2* __restrict__ part, const int* __restrict__ bbase,
                                  float* __restrict__ dinv, int* __restrict__ rowptr,
                                  unsigned* __restrict__ final_e, int n) {
    __shared__ int   hist[NPB];
    __shared__ float wsum[NPB];
    __shared__ int   nbase[NPB];
    __shared__ int   cur[NPB];
    int b = blockIdx.x, t = threadIdx.x;
    if (t < NPB) { hist[t] = 0; wsum[t] = 0.0f; }
    __syncthreads();
    int s = bbase[b], e = bbase[b + 1];
    for (int i = s + t; i < e; i += 256) {
        int2 rec = part[i];
        int cl = rec.x >> 16;
        atomicAdd(&hist[cl], 1);
        atomicAdd(&wsum[cl], __int_as_float(rec.y));
    }
    __syncthreads();
    if (t == 0) {
        int run = 0;
        for (int k = 0; k < NPB; ++k) { nbase[k] = run; run += hist[k]; }
    }
    __syncthreads();
    if (t < NPB) {
        int node = b * NPB + t;
        if (node < n) {
            dinv[node] = rsqrtf(1.0f + wsum[t]);   // deg >= 1 (self-loop)
            rowptr[node] = s + nbase[t];
        }
        cur[t] = nbase[t];
    }
    __syncthreads();
    for (int i = s + t; i < e; i += 256) {
        int2 rec = part[i];
        int cl = rec.x >> 16;
        int q = s + atomicAdd(&cur[cl], 1);       // LDS atomic
        unsigned short ws = __half_as_ushort(__float2half_rn(__int_as_float(rec.y)));
        final_e[q] = ((unsigned)rec.x & 0xffffu) | ((unsigned)ws << 16);
    }
}

// MFMA GEMM: C[r][:] = bf16( scale[r] * (A[r][:K] @ B) ), B given transposed
// bf16 as Wt[n][k] ([M][K]). Block: 64 rows x full M, 4 waves. [R7]
template <int K, int M>
__launch_bounds__(256)
__global__ void gemm_mfma_kernel(const float* __restrict__ A,
                                 const unsigned short* __restrict__ Wt,
                                 const float* __restrict__ scale,
                                 unsigned short* __restrict__ C, int N) {
    constexpr int BK = 64, LD = BK + 8;       // LDS k-stride (pad: 2-way-free banks)
    constexpr int WN = M / 4;                 // cols per wave
    constexpr int NT = WN / 16;               // 16x16 n-tiles per wave
    constexpr int CLD = M + 8;
    constexpr int SM = (64 * LD + M * LD) > (64 * CLD) ? (64 * LD + M * LD) : (64 * CLD);
    __shared__ unsigned short smem[SM];
    __shared__ float sdv[64];
    unsigned short* As = smem;                // [64][LD]
    unsigned short* Bs = smem + 64 * LD;      // [M][LD]

    const int tid = threadIdx.x;
    const int row0 = blockIdx.x * 64;
    const int lane = tid & 63;
    const int quad = lane >> 4, r16 = lane & 15;
    const int n0 = (tid >> 6) * WN;

    if (tid < 64) {
        int r = row0 + tid;
        sdv[tid] = (r < N) ? scale[r] : 0.0f;
    }

    f32x4 acc[4][NT];
#pragma unroll
    for (int mt = 0; mt < 4; ++mt)
#pragma unroll
        for (int nt = 0; nt < NT; ++nt)
            acc[mt][nt] = (f32x4){0.f, 0.f, 0.f, 0.f};

    for (int k0 = 0; k0 < K; k0 += BK) {
        // stage A: 64 rows x 64 k, fp32 -> bf16 (1024 float4, 4/thread)
#pragma unroll
        for (int j = 0; j < 4; ++j) {
            int idx = tid + j * 256;
            int m = idx >> 4;
            int q = idx & 15;
            int gr = row0 + m;
            float4 v = make_float4(0.f, 0.f, 0.f, 0.f);
            if (gr < N) v = *(const float4*)&A[(size_t)gr * K + k0 + q * 4];
            ushort4 s4;
            s4.x = f2bf(v.x); s4.y = f2bf(v.y); s4.z = f2bf(v.z); s4.w = f2bf(v.w);
            *(ushort4*)&As[m * LD + q * 4] = s4;
        }
        // stage B: M rows(n) x 64 k bf16 (uint4 = 8 bf16)
#pragma unroll
        for (int j = 0; j < M * 8 / 256; ++j) {
            int idx = tid + j * 256;
            int nn = idx >> 3;
            int q = idx & 7;
            uint4 v = *(const uint4*)&Wt[(size_t)nn * K + k0 + q * 8];
            *(uint4*)&Bs[nn * LD + q * 8] = v;
        }
        __syncthreads();
#pragma unroll
        for (int ks = 0; ks < BK / 32; ++ks) {
            bf16x8 af[4], bfr[NT];
#pragma unroll
            for (int nt = 0; nt < NT; ++nt)
                bfr[nt] = *(const bf16x8*)&Bs[(n0 + nt * 16 + r16) * LD + ks * 32 + quad * 8];
#pragma unroll
            for (int mt = 0; mt < 4; ++mt)
                af[mt] = *(const bf16x8*)&As[(mt * 16 + r16) * LD + ks * 32 + quad * 8];
#pragma unroll
            for (int mt = 0; mt < 4; ++mt)
#pragma unroll
                for (int nt = 0; nt < NT; ++nt)
                    acc[mt][nt] = __builtin_amdgcn_mfma_f32_16x16x32_bf16(
                        af[mt], bfr[nt], acc[mt][nt], 0, 0, 0);
        }
        __syncthreads();
    }
    // epilogue: scale, bf16, LDS transpose-stage for coalesced stores
    unsigned short* Cs = smem;                // [64][CLD]
#pragma unroll
    for (int mt = 0; mt < 4; ++mt) {
#pragma unroll
        for (int i = 0; i < 4; ++i) {
            int r = mt * 16 + quad * 4 + i;
            float sc = sdv[r];
#pragma unroll
            for (int nt = 0; nt < NT; ++nt)
                Cs[r * CLD + n0 + nt * 16 + r16] = f2bf(acc[mt][nt][i] * sc);
        }
    }
    __syncthreads();
#pragma unroll
    for (int j = 0; j < 64 * M / 8 / 256; ++j) {
        int idx = tid + j * 256;
        int r = idx / (M / 8);
        int q = idx % (M / 8);
        int gr = row0 + r;
        if (gr < N) {
            uint4 v = *(const uint4*)&Cs[r * CLD + q * 8];
            *(uint4*)&C[(size_t)gr * M + q * 8] = v;
        }
    }
}

#define ACC8(v, wgt)                                            \
    a0 += (wgt) * bflo((v).x); a1 += (wgt) * bfhi((v).x);       \
    a2 += (wgt) * bflo((v).y); a3 += (wgt) * bfhi((v).y);       \
    a4 += (wgt) * bflo((v).z); a5 += (wgt) * bfhi((v).z);       \
    a6 += (wgt) * bflo((v).w); a7 += (wgt) * bfhi((v).w);

// Layer-1 aggregation [R7]: 1 wave/node, 4 slots x 16 lanes, uint4 full-row
// gathers (256B/row, 16 edges/round), 2-deep pipeline, clamped tail.
__launch_bounds__(256, 6)
__global__ void agg1_kernel(const unsigned short* __restrict__ xw,   // bf16 [n][128] (pre-scaled)
                            const int* __restrict__ rowptr,
                            const unsigned* __restrict__ edge,       // src|half(w)<<16
                            const float* __restrict__ dinv,
                            const float* __restrict__ bias,          // fp32 [128]
                            float* __restrict__ out, int n) {        // fp32 [n][128]
    int node = blockIdx.x * 4 + (threadIdx.x >> 6);
    if (node >= n) return;
    int lane = threadIdx.x & 63;
    int qw = lane >> 4, sub = lane & 15;
    const char* xb = (const char*)xw;
    const unsigned ssub = (unsigned)sub << 4;       // byte offset in 256B row
    float di = dinv[node];

    float a0 = 0.f, a1 = 0.f, a2 = 0.f, a3 = 0.f;
    float a4 = 0.f, a5 = 0.f, a6 = 0.f, a7 = 0.f;
    if (qw == 0) {                                   // self term, weight 1
        uint4 u = *(const uint4*)(xb + (((unsigned)node) << 8) + ssub);
        a0 = bflo(u.x); a1 = bfhi(u.x); a2 = bflo(u.y); a3 = bfhi(u.y);
        a4 = bflo(u.z); a5 = bfhi(u.z); a6 = bflo(u.w); a7 = bfhi(u.w);
    }

    int p = rowptr[node], p1 = rowptr[node + 1];
    int sb = 4 * qw;
    unsigned r0, r1, r2, r3;
    uint4 v0, v1, v2, v3;
    bool have = (p + 16 <= p1);
    if (have) {
        const unsigned* rp = edge + p + sb;
        r0 = __builtin_nontemporal_load(rp);
        r1 = __builtin_nontemporal_load(rp + 1);
        r2 = __builtin_nontemporal_load(rp + 2);
        r3 = __builtin_nontemporal_load(rp + 3);
        v0 = *(const uint4*)(xb + ((r0 & 0xffffu) << 8) + ssub);
        v1 = *(const uint4*)(xb + ((r1 & 0xffffu) << 8) + ssub);
        v2 = *(const uint4*)(xb + ((r2 & 0xffffu) << 8) + ssub);
        v3 = *(const uint4*)(xb + ((r3 & 0xffffu) << 8) + ssub);
    }
#pragma unroll 1
    while (have) {
        p += 16;
        bool havn = (p + 16 <= p1);
        unsigned m0 = 0, m1 = 0, m2 = 0, m3 = 0;
        uint4 u0 = {0,0,0,0}, u1 = {0,0,0,0}, u2 = {0,0,0,0}, u3 = {0,0,0,0};
        if (havn) {                                  // next records + gathers
            const unsigned* rp = edge + p + sb;
            m0 = __builtin_nontemporal_load(rp);
            m1 = __builtin_nontemporal_load(rp + 1);
            m2 = __builtin_nontemporal_load(rp + 2);
            m3 = __builtin_nontemporal_load(rp + 3);
            u0 = *(const uint4*)(xb + ((m0 & 0xffffu) << 8) + ssub);
            u1 = *(const uint4*)(xb + ((m1 & 0xffffu) << 8) + ssub);
            u2 = *(const uint4*)(xb + ((m2 & 0xffffu) << 8) + ssub);
            u3 = *(const uint4*)(xb + ((m3 & 0xffffu) << 8) + ssub);
        }
        float w0 = wdec(r0), w1 = wdec(r1), w2 = wdec(r2), w3 = wdec(r3);
        ACC8(v0, w0); ACC8(v1, w1); ACC8(v2, w2); ACC8(v3, w3);
        r0 = m0; r1 = m1; r2 = m2; r3 = m3;
        v0 = u0; v1 = u1; v2 = u2; v3 = u3;
        have = havn;
    }
    int rem = p1 - p;                                // 0..15, one clamped round
    if (rem > 0) {
        int last = p1 - 1, b = p + sb;
        unsigned e0 = edge[min(b, last)],     e1 = edge[min(b + 1, last)];
        unsigned e2 = edge[min(b + 2, last)], e3 = edge[min(b + 3, last)];
        float w0 = (b     <= last) ? wdec(e0) : 0.f;
        float w1 = (b + 1 <= last) ? wdec(e1) : 0.f;
        float w2 = (b + 2 <= last) ? wdec(e2) : 0.f;
        float w3 = (b + 3 <= last) ? wdec(e3) : 0.f;
        uint4 t0 = *(const uint4*)(xb + ((e0 & 0xffffu) << 8) + ssub);
        uint4 t1 = *(const uint4*)(xb + ((e1 & 0xffffu) << 8) + ssub);
        uint4 t2 = *(const uint4*)(xb + ((e2 & 0xffffu) << 8) + ssub);
        uint4 t3 = *(const uint4*)(xb + ((e3 & 0xffffu) << 8) + ssub);
        ACC8(t0, w0); ACC8(t1, w1); ACC8(t2, w2); ACC8(t3, w3);
    }
    // reduce over the 4 slots (lane bits 4,5)
    a0 += __shfl_xor(a0, 16); a0 += __shfl_xor(a0, 32);
    a1 += __shfl_xor(a1, 16); a1 += __shfl_xor(a1, 32);
    a2 += __shfl_xor(a2, 16); a2 += __shfl_xor(a2, 32);
    a3 += __shfl_xor(a3, 16); a3 += __shfl_xor(a3, 32);
    a4 += __shfl_xor(a4, 16); a4 += __shfl_xor(a4, 32);
    a5 += __shfl_xor(a5, 16); a5 += __shfl_xor(a5, 32);
    a6 += __shfl_xor(a6, 16); a6 += __shfl_xor(a6, 32);
    a7 += __shfl_xor(a7, 16); a7 += __shfl_xor(a7, 32);
    if (qw < 2) {
        float4 b = ((const float4*)bias)[2 * sub + qw];
        f32x4 o;
        if (qw == 0) { o.x = a0; o.y = a1; o.z = a2; o.w = a3; }
        else         { o.x = a4; o.y = a5; o.z = a6; o.w = a7; }
        o.x = fmaxf(di * o.x + b.x, 0.f);
        o.y = fmaxf(di * o.y + b.y, 0.f);
        o.z = fmaxf(di * o.z + b.z, 0.f);
        o.w = fmaxf(di * o.w + b.w, 0.f);
        __builtin_nontemporal_store(o, (f32x4*)out + (size_t)node * 32 + 2 * sub + qw);
    }
}

// Layer-2 aggregation + log_softmax [R7]: 8 slots x 8 lanes, 2-deep pipeline.
__launch_bounds__(256, 6)
__global__ void agg2_kernel(const unsigned short* __restrict__ xw,   // bf16 [n][64] (pre-scaled)
                            const int* __restrict__ rowptr,
                            const unsigned* __restrict__ edge,
                            const float* __restrict__ dinv,
                            const float* __restrict__ bias,          // fp32 [64]
                            float* __restrict__ out, int n) {        // fp32 [n][64]
    int node = blockIdx.x * 4 + (threadIdx.x >> 6);
    if (node >= n) return;
    int lane = threadIdx.x & 63;
    int oct = lane >> 3, sub = lane & 7;
    const char* xb = (const char*)xw;
    const unsigned ssub = (unsigned)sub << 4;       // byte offset in 128B row
    float di = dinv[node];

    float a0 = 0.f, a1 = 0.f, a2 = 0.f, a3 = 0.f;
    float a4 = 0.f, a5 = 0.f, a6 = 0.f, a7 = 0.f;
    if (oct == 0) {                                  // self term, weight 1
        uint4 u = *(const uint4*)(xb + (((unsigned)node) << 7) + ssub);
        a0 = bflo(u.x); a1 = bfhi(u.x); a2 = bflo(u.y); a3 = bfhi(u.y);
        a4 = bflo(u.z); a5 = bfhi(u.z); a6 = bflo(u.w); a7 = bfhi(u.w);
    }

    int p = rowptr[node], p1 = rowptr[node + 1];
    int sb = 4 * oct;
    unsigned r0, r1, r2, r3;
    uint4 v0, v1, v2, v3;
    bool have = (p + 32 <= p1);
    if (have) {
        const unsigned* rp = edge + p + sb;
        r0 = __builtin_nontemporal_load(rp);
        r1 = __builtin_nontemporal_load(rp + 1);
        r2 = __builtin_nontemporal_load(rp + 2);
        r3 = __builtin_nontemporal_load(rp + 3);
        v0 = *(const uint4*)(xb + ((r0 & 0xffffu) << 7) + ssub);
        v1 = *(const uint4*)(xb + ((r1 & 0xffffu) << 7) + ssub);
        v2 = *(const uint4*)(xb + ((r2 & 0xffffu) << 7) + ssub);
        v3 = *(const uint4*)(xb + ((r3 & 0xffffu) << 7) + ssub);
    }
#pragma unroll 1
    while (have) {
        p += 32;
        bool havn = (p + 32 <= p1);
        unsigned m0 = 0, m1 = 0, m2 = 0, m3 = 0;
        uint4 u0 = {0,0,0,0}, u1 = {0,0,0,0}, u2 = {0,0,0,0}, u3 = {0,0,0,0};
        if (havn) {
            const unsigned* rp = edge + p + sb;
            m0 = __builtin_nontemporal_load(rp);
            m1 = __builtin_nontemporal_load(rp + 1);
            m2 = __builtin_nontemporal_load(rp + 2);
            m3 = __builtin_nontemporal_load(rp + 3);
            u0 = *(const uint4*)(xb + ((m0 & 0xffffu) << 7) + ssub);
            u1 = *(const uint4*)(xb + ((m1 & 0xffffu) << 7) + ssub);
            u2 = *(const uint4*)(xb + ((m2 & 0xffffu) << 7) + ssub);
            u3 = *(const uint4*)(xb + ((m3 & 0xffffu) << 7) + ssub);
        }
        float w0 = wdec(r0), w1 = wdec(r1), w2 = wdec(r2), w3 = wdec(r3);
        ACC8(v0, w0); ACC8(v1, w1); ACC8(v2, w2); ACC8(v3, w3);
        r0 = m0; r1 = m1; r2 = m2; r3 = m3;
        v0 = u0; v1 = u1; v2 = u2; v3 = u3;
        have = havn;
    }
    int rem = p1 - p;                                // 0..31, one clamped round
    if (rem > 0) {
        int last = p1 - 1, b = p + sb;
        unsigned e0 = edge[min(b, last)],     e1 = edge[min(b + 1, last)];
        unsigned e2 = edge[min(b + 2, last)], e3 = edge[min(b + 3, last)];
        float w0 = (b     <= last) ? wdec(e0) : 0.f;
        float w1 = (b + 1 <= last) ? wdec(e1) : 0.f;
        float w2 = (b + 2 <= last) ? wdec(e2) : 0.f;
        float w3 = (b + 3 <= last) ? wdec(e3) : 0.f;
        uint4 t0 = *(const uint4*)(xb + ((e0 & 0xffffu) << 7) + ssub);
        uint4 t1 = *(const uint4*)(xb + ((e1 & 0xffffu) << 7) + ssub);
        uint4 t2 = *(const uint4*)(xb + ((e2 & 0xffffu) << 7) + ssub);
        uint4 t3 = *(const uint4*)(xb + ((e3 & 0xffffu) << 7) + ssub);
        ACC8(t0, w0); ACC8(t1, w1); ACC8(t2, w2); ACC8(t3, w3);
    }
    // reduce over the 8 slots (lane bits 3,4,5)
    a0 += __shfl_xor(a0, 8); a0 += __shfl_xor(a0, 16); a0 += __shfl_xor(a0, 32);
    a1 += __shfl_xor(a1, 8); a1 += __shfl_xor(a1, 16); a1 += __shfl_xor(a1, 32);
    a2 += __shfl_xor(a2, 8); a2 += __shfl_xor(a2, 16); a2 += __shfl_xor(a2, 32);
    a3 += __shfl_xor(a3, 8); a3 += __shfl_xor(a3, 16); a3 += __shfl_xor(a3, 32);
    a4 += __shfl_xor(a4, 8); a4 += __shfl_xor(a4, 16); a4 += __shfl_xor(a4, 32);
    a5 += __shfl_xor(a5, 8); a5 += __shfl_xor(a5, 16); a5 += __shfl_xor(a5, 32);
    a6 += __shfl_xor(a6, 8); a6 += __shfl_xor(a6, 16); a6 += __shfl_xor(a6, 32);
    a7 += __shfl_xor(a7, 8); a7 += __shfl_xor(a7, 16); a7 += __shfl_xor(a7, 32);
    // bias + dinv, then log_softmax over the 64 features
    const float4* bp = (const float4*)bias;
    float4 bl = bp[2 * sub], bh = bp[2 * sub + 1];
    a0 = di * a0 + bl.x; a1 = di * a1 + bl.y; a2 = di * a2 + bl.z; a3 = di * a3 + bl.w;
    a4 = di * a4 + bh.x; a5 = di * a5 + bh.y; a6 = di * a6 + bh.z; a7 = di * a7 + bh.w;
    float m = fmaxf(fmaxf(fmaxf(a0, a1), fmaxf(a2, a3)),
                    fmaxf(fmaxf(a4, a5), fmaxf(a6, a7)));
    m = fmaxf(m, __shfl_xor(m, 4));
    m = fmaxf(m, __shfl_xor(m, 2));
    m = fmaxf(m, __shfl_xor(m, 1));
    float s = __expf(a0 - m) + __expf(a1 - m) + __expf(a2 - m) + __expf(a3 - m)
            + __expf(a4 - m) + __expf(a5 - m) + __expf(a6 - m) + __expf(a7 - m);
    s += __shfl_xor(s, 4);
    s += __shfl_xor(s, 2);
    s += __shfl_xor(s, 1);
    float lse = m + __logf(s);
    if (oct < 2) {
        f32x4 o;
        if (oct == 0) { o.x = a0 - lse; o.y = a1 - lse; o.z = a2 - lse; o.w = a3 - lse; }
        else          { o.x = a4 - lse; o.y = a5 - lse; o.z = a6 - lse; o.w = a7 - lse; }
        __builtin_nontemporal_store(o, (f32x4*)out + (size_t)node * 16 + 2 * sub + oct);
    }
}

extern "C" void kernel_launch(void* const* d_in, const int* in_sizes, int n_in,
                              void* d_out, int out_size, void* d_ws, size_t ws_size,
                              hipStream_t stream) {
    const float* x  = (const float*)d_in[0];
    const int*   ei = (const int*)d_in[1];
    const float* ew = (const float*)d_in[2];
    const float* W1 = (const float*)d_in[3];
    const float* b1 = (const float*)d_in[4];
    const float* W2 = (const float*)d_in[5];
    const float* b2 = (const float*)d_in[6];
    float* out = (float*)d_out;

    const int n = in_sizes[0] / DIN;      // 50000
    const int E = in_sizes[2];            // 1600000
    const int* row = ei;                  // edge_index[0] (source)
    const int* col = ei + E;              // edge_index[1] (target)

    const int NB = (n + NPB - 1) / NPB;   // 500 buckets
    const int P  = NB;
    const int Ec = (E + P - 1) / P;       // 3200 edges/block

    char* ptr = (char*)d_ws;
    auto alloc = [&](size_t bytes) -> void* {
        void* r = (void*)ptr;
        ptr += (bytes + 255) & ~(size_t)255;
        return r;
    };
    int*   bh     = (int*)  alloc((size_t)P * NB * 4);       // 1 MB
    int*   btotal = (int*)  alloc((size_t)NB * 4);
    int*   bbase  = (int*)  alloc((size_t)(NB + 1) * 4);
    int*   rowptr = (int*)  alloc((size_t)(n + 1) * 4);
    float* dinv   = (float*)alloc((size_t)n * 4);
    unsigned* edge = (unsigned*)alloc((size_t)E * 4);        // packed CSR edges
    unsigned short* xw1 = (unsigned short*)alloc((size_t)n * DH * 2);  // bf16 tables
    unsigned short* wt1 = (unsigned short*)alloc((size_t)DH * DIN * 2);
    unsigned short* wt2 = (unsigned short*)alloc((size_t)DOUT * DH * 2);
    // tail: part (12.8MB, build phase) then h1 (25.6MB, compute phase)
    char* tail = (char*)alloc((size_t)n * DH * 4);
    int2*  part = (int2*)tail;
    float* h1   = (float*)tail;
    unsigned short* xw2 = xw1;            // layer-2 table aliases layer-1 table

    const int nb_g = (n + 63) / 64;       // 782
    const int nb_a = (n + 3) / 4;         // 12500
    const int prepb = (DH * DIN + DOUT * DH + 255) / 256;    // 160

    kernelA<<<P + prepb, 256, 0, stream>>>(col, bh, E, Ec, NB, P, W1, W2, wt1, wt2);
    colscan_kernel<<<NB, 512, 0, stream>>>(bh, btotal, P, NB);
    scatter_kernel<<<P, 256, 0, stream>>>(row, col, ew, bh, btotal, bbase, rowptr, part, E, Ec, NB, n);
    bucket_csr_kernel<<<NB, 256, 0, stream>>>(part, bbase, dinv, rowptr, edge, n);

    gemm_mfma_kernel<DIN, DH><<<nb_g, 256, 0, stream>>>(x, wt1, dinv, xw1, n);
    agg1_kernel<<<nb_a, 256, 0, stream>>>(xw1, rowptr, edge, dinv, b1, h1, n);
    gemm_mfma_kernel<DH, DOUT><<<nb_g, 256, 0, stream>>>(h1, wt2, dinv, xw2, n);
    agg2_kernel<<<nb_a, 256, 0, stream>>>(xw2, rowptr, edge, dinv, b2, out, n);
}